// Round 3
// baseline (67.197 us; speedup 1.0000x reference)
//
#include <hip/hip_runtime.h>

// NeRF volumetric alpha-compositing: one wave (64 lanes) per ray.
// Lane l owns samples l and l+64 of the 128 samples.
// rgbo: [N, S, 4] f32 (rgb raw + density), depth: [N, S] f32 sorted.
// out:  [N, 3] f32 composited color.
//
// NOTE: exclusive scan is computed as shfl_up(inclusive,1), NOT as
// (inclusive - m). The last sample's m = -sigma*1e9; subtracting it back
// from the inclusive sum loses ~64 ULP at 1e9 magnitude, and exp() of that
// rounding error exploded to ~e^31 (round 1/2 failure, absmax 2.6e13).

#define NERF_N_SAMPLES 128
#define NERF_FAR_DELTA 1e9f

__device__ __forceinline__ float sigmoidf_fast(float x) {
    return 1.0f / (1.0f + __expf(-x));
}

__global__ __launch_bounds__(256) void nerf_render_kernel(
    const float4* __restrict__ rgbo,   // [N, S] of float4
    const float*  __restrict__ depth,  // [N, S]
    float*        __restrict__ out,    // [N, 3]
    int n_rays)
{
    const int gtid = blockIdx.x * blockDim.x + threadIdx.x;
    const int ray  = gtid >> 6;         // one wave64 per ray
    const int lane = threadIdx.x & 63;
    if (ray >= n_rays) return;

    // ---- coalesced loads: lane l -> samples l and l+64 ----
    const float4* rbase = rgbo + (size_t)ray * NERF_N_SAMPLES;
    const float4 ra = rbase[lane];        // sample l
    const float4 rb = rbase[lane + 64];   // sample l+64

    const float* dbase = depth + (size_t)ray * NERF_N_SAMPLES;
    const float da = dbase[lane];
    const float db = dbase[lane + 64];

    // ---- deltas (next-sample depth via cross-lane shuffle) ----
    const float da_next = __shfl_down(da, 1, 64);   // depth[l+1]  (junk at lane 63)
    const float db_next = __shfl_down(db, 1, 64);   // depth[l+65] (junk at lane 63)
    const float d64     = __shfl(db, 0, 64);        // depth[64] broadcast

    const float delta_a = (lane == 63) ? (d64 - da)      : (da_next - da);
    const float delta_b = (lane == 63) ? NERF_FAR_DELTA  : (db_next - db);

    const float m_a = -ra.w * delta_a;   // mult for sample l     (<= 0)
    const float m_b = -rb.w * delta_b;   // mult for sample l+64  (<= 0, ~-1e9 at lane 63)

    // ---- inclusive wave scans (Hillis-Steele) ----
    float sa = m_a;
    #pragma unroll
    for (int off = 1; off < 64; off <<= 1) {
        float y = __shfl_up(sa, off, 64);
        if (lane >= off) sa += y;
    }
    float sb = m_b;
    #pragma unroll
    for (int off = 1; off < 64; off <<= 1) {
        float y = __shfl_up(sb, off, 64);
        if (lane >= off) sb += y;
    }

    // ---- exclusive scans WITHOUT subtraction (see NOTE above) ----
    const float excl_a_raw = __shfl_up(sa, 1, 64);   // junk at lane 0
    const float excl_b_raw = __shfl_up(sb, 1, 64);   // junk at lane 0
    const float excl_a = (lane == 0) ? 0.0f : excl_a_raw;
    const float total_a = __shfl(sa, 63, 64);        // sum of first 64 mults
    const float excl_b = total_a + ((lane == 0) ? 0.0f : excl_b_raw);

    // ---- weights: T*alpha = exp(P) - exp(P+m); P<=0, P+m<=P ----
    const float w_a = __expf(excl_a) - __expf(excl_a + m_a);
    const float w_b = __expf(excl_b) - __expf(excl_b + m_b);

    // ---- weighted sigmoid(rgb) accumulation ----
    float c0 = w_a * sigmoidf_fast(ra.x) + w_b * sigmoidf_fast(rb.x);
    float c1 = w_a * sigmoidf_fast(ra.y) + w_b * sigmoidf_fast(rb.y);
    float c2 = w_a * sigmoidf_fast(ra.z) + w_b * sigmoidf_fast(rb.z);

    // ---- wave reduction across 64 lanes ----
    #pragma unroll
    for (int off = 32; off > 0; off >>= 1) {
        c0 += __shfl_xor(c0, off, 64);
        c1 += __shfl_xor(c1, off, 64);
        c2 += __shfl_xor(c2, off, 64);
    }

    if (lane == 0) {
        float* o = out + (size_t)ray * 3;
        o[0] = c0;
        o[1] = c1;
        o[2] = c2;
    }
}

extern "C" void kernel_launch(void* const* d_in, const int* in_sizes, int n_in,
                              void* d_out, int out_size, void* d_ws, size_t ws_size,
                              hipStream_t stream) {
    // Runtime input disambiguation: rgbo is [N,S,4] (4x elements of depth [N,S]).
    const long long s0 = in_sizes[0];
    const long long s1 = in_sizes[1];

    const float4* rgbo;
    const float*  depth;
    long long depth_elems;
    if (s0 >= 4 * s1) {           // d_in[0] is rgbo
        rgbo  = (const float4*)d_in[0];
        depth = (const float*)d_in[1];
        depth_elems = s1;
    } else {                      // d_in[0] is depth
        rgbo  = (const float4*)d_in[1];
        depth = (const float*)d_in[0];
        depth_elems = s0;
    }
    const int n_rays = (int)(depth_elems / NERF_N_SAMPLES);

    float* out = (float*)d_out;

    const int block = 256;
    const int rays_per_block = block / 64;   // 4 rays per block
    const int grid = (n_rays + rays_per_block - 1) / rays_per_block;

    nerf_render_kernel<<<grid, block, 0, stream>>>(rgbo, depth, out, n_rays);
}

// Round 4
// 59.128 us; speedup vs baseline: 1.1365x; 1.1365x over previous
//
#include <hip/hip_runtime.h>

// NeRF volumetric alpha-compositing: one wave (64 lanes) per ray.
// PAIR layout: lane l owns samples 2l and 2l+1 (contiguous), so
//   - delta0 is lane-local, only 1 shuffle needed for deltas
//   - one 6-step wave scan covers all 128 samples (vs two scans)
//   - transmittance chain T0,T1,T2 shared: 3 exps per pair (vs 4)
// rgbo: [N, S, 4] f32 (raw rgb + density), depth: [N, S] f32 sorted.
// out:  [N, 3] f32.
//
// NOTE (round-2 lesson): exclusive scan via shfl_up(inclusive,1), never
// (inclusive - m): lane 63's m = -sigma*1e9 and the subtraction's rounding
// error (~64 ULP at 1e9) explodes through exp() -> absmax 2.6e13.

#define NERF_N_SAMPLES 128
#define NERF_FAR_DELTA 1e9f

__device__ __forceinline__ float fast_rcp(float x) {
    return __builtin_amdgcn_rcpf(x);   // v_rcp_f32, 1 inst (vs ~10 for precise div)
}

__device__ __forceinline__ float sigmoidf_fast(float x) {
    return fast_rcp(1.0f + __expf(-x));
}

__global__ __launch_bounds__(256) void nerf_render_kernel(
    const float4* __restrict__ rgbo,   // [N, S] of float4
    const float*  __restrict__ depth,  // [N, S]
    float*        __restrict__ out,    // [N, 3]
    int n_rays)
{
    const int gtid = blockIdx.x * blockDim.x + threadIdx.x;
    const int ray  = gtid >> 6;         // one wave64 per ray
    const int lane = threadIdx.x & 63;
    if (ray >= n_rays) return;

    // ---- coalesced loads: lane l -> samples 2l, 2l+1 ----
    const float4* rbase = rgbo + (size_t)ray * NERF_N_SAMPLES;
    const float4 r0 = rbase[2 * lane];
    const float4 r1 = rbase[2 * lane + 1];

    const float2 d = *reinterpret_cast<const float2*>(
        depth + (size_t)ray * NERF_N_SAMPLES + 2 * lane);

    // ---- deltas: delta0 local; delta1 needs next lane's d.x ----
    const float d_next = __shfl_down(d.x, 1, 64);    // depth[2l+2] (junk at lane 63)
    const float delta0 = d.y - d.x;
    const float delta1 = (lane == 63) ? NERF_FAR_DELTA : (d_next - d.y);

    const float m0 = -r0.w * delta0;   // <= 0
    const float m1 = -r1.w * delta1;   // <= 0 (~-1e9 at lane 63)
    const float mp = m0 + m1;          // pair-combined mult

    // ---- single inclusive wave scan over pair sums ----
    float s = mp;
    #pragma unroll
    for (int off = 1; off < 64; off <<= 1) {
        float y = __shfl_up(s, off, 64);
        s += (lane >= off) ? y : 0.0f;
    }

    // exclusive prefix for sample 2l (shuffle, not subtraction — see NOTE)
    const float excl_raw = __shfl_up(s, 1, 64);
    const float P0 = (lane == 0) ? 0.0f : excl_raw;  // sum m[0..2l)
    const float P1 = P0 + m0;                        // sum m[0..2l+1)

    // ---- weights via shared transmittance chain: w_i = T_i - T_{i+1} ----
    const float T0 = __expf(P0);
    const float T1 = __expf(P1);
    const float T2 = __expf(P1 + m1);
    const float w0 = T0 - T1;
    const float w1 = T1 - T2;

    // ---- weighted sigmoid(rgb) accumulation ----
    float c0 = w0 * sigmoidf_fast(r0.x) + w1 * sigmoidf_fast(r1.x);
    float c1 = w0 * sigmoidf_fast(r0.y) + w1 * sigmoidf_fast(r1.y);
    float c2 = w0 * sigmoidf_fast(r0.z) + w1 * sigmoidf_fast(r1.z);

    // ---- butterfly reduce: afterwards ALL lanes hold the sums ----
    #pragma unroll
    for (int off = 32; off > 0; off >>= 1) {
        c0 += __shfl_xor(c0, off, 64);
        c1 += __shfl_xor(c1, off, 64);
        c2 += __shfl_xor(c2, off, 64);
    }

    // lanes 0,1,2 each store one channel (single store inst for the wave)
    if (lane < 3) {
        const float v = (lane == 0) ? c0 : (lane == 1) ? c1 : c2;
        out[(size_t)ray * 3 + lane] = v;
    }
}

extern "C" void kernel_launch(void* const* d_in, const int* in_sizes, int n_in,
                              void* d_out, int out_size, void* d_ws, size_t ws_size,
                              hipStream_t stream) {
    // Runtime input disambiguation: rgbo is [N,S,4] (4x elements of depth [N,S]).
    const long long s0 = in_sizes[0];
    const long long s1 = in_sizes[1];

    const float4* rgbo;
    const float*  depth;
    long long depth_elems;
    if (s0 >= 4 * s1) {           // d_in[0] is rgbo
        rgbo  = (const float4*)d_in[0];
        depth = (const float*)d_in[1];
        depth_elems = s1;
    } else {                      // d_in[0] is depth
        rgbo  = (const float4*)d_in[1];
        depth = (const float*)d_in[0];
        depth_elems = s0;
    }
    const int n_rays = (int)(depth_elems / NERF_N_SAMPLES);

    float* out = (float*)d_out;

    const int block = 256;                   // 4 rays per block
    const int rays_per_block = block / 64;
    const int grid = (n_rays + rays_per_block - 1) / rays_per_block;

    nerf_render_kernel<<<grid, block, 0, stream>>>(rgbo, depth, out, n_rays);
}